// Round 8
// baseline (855.385 us; speedup 1.0000x reference)
//
#include <hip/hip_runtime.h>
#include <hip/hip_bf16.h>

#define NN 4096

typedef unsigned short u16;
using bf16x8 = __attribute__((ext_vector_type(8))) short;
using f32x16 = __attribute__((ext_vector_type(16))) float;
using u32x4  = __attribute__((ext_vector_type(4))) unsigned int;

// round-to-nearest-even f32 -> bf16 bits
__device__ inline u16 f2bf(float f) {
    union { float f; unsigned u; } c; c.f = f;
    unsigned r = (c.u + 0x7fffu + ((c.u >> 16) & 1u)) >> 16;
    return (u16)r;
}

__device__ inline void gld16(const void* g, void* l) {
    __builtin_amdgcn_global_load_lds(
        (const __attribute__((address_space(1))) void*)g,
        (__attribute__((address_space(3))) void*)l, 16, 0, 0);
}

__device__ inline bf16x8 negbf(bf16x8 v) {
    u32x4 u; __builtin_memcpy(&u, &v, 16);
    u ^= 0x80008000u;
    bf16x8 r; __builtin_memcpy(&r, &u, 16);
    return r;
}

// Bijective XCD-region block swizzle.
__device__ inline void swz_tile(int bid, int& brow, int& bcol) {
    const int xcd   = bid & 7;
    const int local = bid >> 3;
    const int rr    = xcd >> 1;
    const int rc    = xcd & 1;
    brow = (rr * 8  + (local >> 4)) * 128;
    bcol = (rc * 16 + (local & 15)) * 128;
}

// ---------------- f32 -> bf16 convert ----------------
__global__ __launch_bounds__(256) void cvt_bf16(const float* __restrict__ s,
                                                u16* __restrict__ d) {
    size_t i = ((size_t)blockIdx.x * 256 + threadIdx.x) * 8;
    float4 v0 = *(const float4*)(s + i);
    float4 v1 = *(const float4*)(s + i + 4);
    bf16x8 o;
    o[0] = (short)f2bf(v0.x); o[1] = (short)f2bf(v0.y);
    o[2] = (short)f2bf(v0.z); o[3] = (short)f2bf(v0.w);
    o[4] = (short)f2bf(v1.x); o[5] = (short)f2bf(v1.y);
    o[6] = (short)f2bf(v1.z); o[7] = (short)f2bf(v1.w);
    *(bf16x8*)(d + i) = o;
}

// ---------------- transpose + convert: d[m][k] = bf16(s[k][m]) ----------------
__global__ __launch_bounds__(256) void tr_cvt(const float* __restrict__ s,
                                              u16* __restrict__ d) {
    __shared__ float t[32][33];
    int x  = blockIdx.x * 32 + threadIdx.x;
    int y0 = blockIdx.y * 32;
#pragma unroll
    for (int j = 0; j < 32; j += 8)
        t[threadIdx.y + j][threadIdx.x] = s[(size_t)(y0 + threadIdx.y + j) * NN + x];
    __syncthreads();
    int x2 = blockIdx.y * 32 + threadIdx.x;
    int y2 = blockIdx.x * 32;
#pragma unroll
    for (int j = 0; j < 32; j += 8)
        d[(size_t)(y2 + threadIdx.y + j) * NN + x2] = f2bf(t[threadIdx.x][threadIdx.y + j]);
}

// ---- phase primitives (rule #18: sched_barrier after inline waitcnt) ----
#define P_BAR  __builtin_amdgcn_s_barrier()
#define P_LGKM do { asm volatile("s_waitcnt lgkmcnt(0)" ::: "memory"); \
                    __builtin_amdgcn_sched_barrier(0); } while (0)
#define P_VM0  do { asm volatile("s_waitcnt vmcnt(0)" ::: "memory"); \
                    __builtin_amdgcn_sched_barrier(0); } while (0)

#define MF32(a_, b_, c_) __builtin_amdgcn_mfma_f32_32x32x16_bf16(a_, b_, c_, 0, 0, 0)

// one 64x64 chain over BK=32: 4 independent MFMA, then 4 at dependency
// distance 4 (32x32 MFMA ~8cyc issue -> no b2b dependent stall)
#define CHAIN32(A, B, ACC) do { \
    ACC[0][0] = MF32(A##00, B##00, ACC[0][0]); \
    ACC[0][1] = MF32(A##00, B##10, ACC[0][1]); \
    ACC[1][0] = MF32(A##10, B##00, ACC[1][0]); \
    ACC[1][1] = MF32(A##10, B##10, ACC[1][1]); \
    ACC[0][0] = MF32(A##01, B##01, ACC[0][0]); \
    ACC[0][1] = MF32(A##01, B##11, ACC[0][1]); \
    ACC[1][0] = MF32(A##11, B##01, ACC[1][0]); \
    ACC[1][1] = MF32(A##11, B##11, ACC[1][1]); \
} while (0)

// LDS permutation: physical 16B-block p at row r holds logical block
// swap01(p ^ ((r>>1)&3)), swap01 = exchange the two index bits (involution).
// The swap01 makes the two k-halves (kh = lane>>5) of one MFMA operand read
// pcols offset by 2, so cross-half lane groups hit disjoint bank-start sets
// (fixes R7's 3.355e7 conflicts; R6's kq=lane>>4 pattern had this for free).
// Staged via inverse-permuted GLOBAL source (gld_lds dest linear, rule #21).

// read 4 frags D{i}{ks}: row = BASE + i*32 + l31 ;
// physical block: ks=0 -> kh2^sxor ; ks=1 -> (kh2|1)^sxor   (kh2 = kh<<1)
#define RDF(D, CC, TILE, BASE) do { \
    const int rA_ = ((BASE) + l31) * 32, rB_ = ((BASE) + 32 + l31) * 32; \
    D##00 = *(const bf16x8*)&sm[CC][TILE][rA_ + ((kh2 ^ sxor) * 8)]; \
    D##01 = *(const bf16x8*)&sm[CC][TILE][rA_ + (((kh2 | 1) ^ sxor) * 8)]; \
    D##10 = *(const bf16x8*)&sm[CC][TILE][rB_ + ((kh2 ^ sxor) * 8)]; \
    D##11 = *(const bf16x8*)&sm[CC][TILE][rB_ + (((kh2 | 1) ^ sxor) * 8)]; \
} while (0)

// ------- pass 1 (FUSED, 2-phase, 32x32x16): Rtr=NT(Wr,x), Rti=NT(Wi,x) -------
__global__ __launch_bounds__(256, 2) void gemm_pass1(
    const u16* __restrict__ Ar, const u16* __restrict__ Ai,
    const u16* __restrict__ B,
    u16* __restrict__ Cr, u16* __restrict__ Ci) {
    __shared__ u16 sm[2][3][4096];   // [buf][Wr,Wi,x] = 48 KB

    int brow, bcol;
    swz_tile(blockIdx.x, brow, bcol);

    const int tid  = threadIdx.x;
    const int lane = tid & 63;
    const int wid  = tid >> 6;
    const int wm   = (wid >> 1) * 64;
    const int wn   = (wid & 1) * 64;
    const int l31  = lane & 31;
    const int kh2  = (lane >> 5) << 1;
    const int sxor = (l31 >> 1) & 3;

    f32x16 accr[2][2] = {};
    f32x16 acci[2][2] = {};

    // staging: thread t -> physical block t&3 at row r0 = t>>2 (+64 for 2nd line)
    // source logical block = swap01((t&3) ^ ((r0>>1)&3))
    const int r0 = tid >> 2;
    const int q0 = (tid & 3) ^ ((r0 >> 1) & 3);
    const int lb = ((q0 & 1) << 1) | (q0 >> 1);
    const size_t aoff0 = (size_t)(brow + r0) * NN + lb * 8;
    const size_t aoff1 = aoff0 + (size_t)64 * NN;
    const size_t boff0 = (size_t)(bcol + r0) * NN + lb * 8;
    const size_t boff1 = boff0 + (size_t)64 * NN;

#define T0(b, kk) gld16(Ar + aoff0 + (kk), &sm[b][0][tid * 8])
#define T1(b, kk) gld16(Ar + aoff1 + (kk), &sm[b][0][2048 + tid * 8])
#define T2(b, kk) gld16(Ai + aoff0 + (kk), &sm[b][1][tid * 8])
#define T3(b, kk) gld16(Ai + aoff1 + (kk), &sm[b][1][2048 + tid * 8])
#define T4(b, kk) gld16(B  + boff0 + (kk), &sm[b][2][tid * 8])
#define T5(b, kk) gld16(B  + boff1 + (kk), &sm[b][2][2048 + tid * 8])

#define KSTEP1(CC, NB, KN, DOSTG) do { \
    bf16x8 ar00, ar01, ar10, ar11, ai00, ai01, ai10, ai11; \
    bf16x8 bx00, bx01, bx10, bx11; \
    RDF(ar, CC, 0, wm); RDF(bx, CC, 2, wn); \
    if (DOSTG) { T0(NB, KN); T1(NB, KN); T2(NB, KN); \
                 T3(NB, KN); T4(NB, KN); T5(NB, KN); } \
    P_BAR; P_LGKM; \
    __builtin_amdgcn_s_setprio(1); \
    CHAIN32(ar, bx, accr); \
    __builtin_amdgcn_s_setprio(0); \
    P_BAR; \
    RDF(ai, CC, 1, wm); \
    P_BAR; P_LGKM; \
    __builtin_amdgcn_s_setprio(1); \
    CHAIN32(ai, bx, acci); \
    __builtin_amdgcn_s_setprio(0); \
    if (DOSTG) P_VM0; \
    P_BAR; \
} while (0)

    T0(0, 0); T1(0, 0); T2(0, 0); T3(0, 0); T4(0, 0); T5(0, 0);
    P_VM0;
    P_BAR;
    for (int t = 0; t < NN / 32 - 1; ++t) {
        const int cc = t & 1, nb = cc ^ 1;
        KSTEP1(cc, nb, (size_t)(t + 1) * 32, 1);
    }
    KSTEP1(1, 0, 0, 0);

    // C/D 32x32: col = l31, row = (e&3) + 8*(e>>2) + 4*kh
    const int kh = kh2 >> 1;
#pragma unroll
    for (int i = 0; i < 2; i++)
#pragma unroll
        for (int j = 0; j < 2; j++) {
            const int col = bcol + wn + j * 32 + l31;
#pragma unroll
            for (int e = 0; e < 16; e++) {
                const int row = brow + wm + i * 32 + (e & 3) + 8 * (e >> 2) + 4 * kh;
                Cr[(size_t)row * NN + col] = f2bf(accr[i][j][e]);
                Ci[(size_t)row * NN + col] = f2bf(acci[i][j][e]);
            }
        }
}

// ------- pass 2 (FUSED dual complex, 2-phase, 32x32x16) ----------------------
// C_r[m,n] = sum_k Ar[m,k]Br[n,k] - Ai[m,k]Bi[n,k]
// C_i[m,n] = sum_k Ar[m,k]Bi[n,k] + Ai[m,k]Br[n,k]
__global__ __launch_bounds__(256, 2) void gemm_pass2(
    const u16* __restrict__ Ar, const u16* __restrict__ Ai,
    const u16* __restrict__ Br, const u16* __restrict__ Bi,
    float* __restrict__ Out) {
    __shared__ u16 sm[2][4][4096];   // [buf][Ar,Ai,Br,Bi] = 64 KB

    int brow, bcol;
    swz_tile(blockIdx.x, brow, bcol);

    const int tid  = threadIdx.x;
    const int lane = tid & 63;
    const int wid  = tid >> 6;
    const int wm   = (wid >> 1) * 64;
    const int wn   = (wid & 1) * 64;
    const int l31  = lane & 31;
    const int kh2  = (lane >> 5) << 1;
    const int sxor = (l31 >> 1) & 3;

    f32x16 accr[2][2] = {};
    f32x16 acci[2][2] = {};

    const int r0 = tid >> 2;
    const int q0 = (tid & 3) ^ ((r0 >> 1) & 3);
    const int lb = ((q0 & 1) << 1) | (q0 >> 1);
    const size_t moff0 = (size_t)(brow + r0) * NN + lb * 8;
    const size_t moff1 = moff0 + (size_t)64 * NN;
    const size_t noff0 = (size_t)(bcol + r0) * NN + lb * 8;
    const size_t noff1 = noff0 + (size_t)64 * NN;

#define SL0(b, kk) gld16(Ar + moff0 + (kk), &sm[b][0][tid * 8])
#define SL1(b, kk) gld16(Ar + moff1 + (kk), &sm[b][0][2048 + tid * 8])
#define SL2(b, kk) gld16(Ai + moff0 + (kk), &sm[b][1][tid * 8])
#define SL3(b, kk) gld16(Ai + moff1 + (kk), &sm[b][1][2048 + tid * 8])
#define SL4(b, kk) gld16(Br + noff0 + (kk), &sm[b][2][tid * 8])
#define SL5(b, kk) gld16(Br + noff1 + (kk), &sm[b][2][2048 + tid * 8])
#define SL6(b, kk) gld16(Bi + noff0 + (kk), &sm[b][3][tid * 8])
#define SL7(b, kk) gld16(Bi + noff1 + (kk), &sm[b][3][2048 + tid * 8])

#define KSTEP2(CC, NB, KN, DOSTG) do { \
    bf16x8 ar00, ar01, ar10, ar11, ai00, ai01, ai10, ai11; \
    bf16x8 br00, br01, br10, br11, bi00, bi01, bi10, bi11; \
    /* Phase A: acci += ar*bi ; accr += ar*br ; issue all 8 stage lines */ \
    RDF(ar, CC, 0, wm); RDF(br, CC, 2, wn); RDF(bi, CC, 3, wn); \
    if (DOSTG) { SL0(NB, KN); SL1(NB, KN); SL2(NB, KN); SL3(NB, KN); \
                 SL4(NB, KN); SL5(NB, KN); SL6(NB, KN); SL7(NB, KN); } \
    P_BAR; P_LGKM; \
    __builtin_amdgcn_s_setprio(1); \
    CHAIN32(ar, bi, acci); \
    CHAIN32(ar, br, accr); \
    __builtin_amdgcn_s_setprio(0); \
    P_BAR; \
    /* Phase B: acci += ai*br ; accr += (-ai)*bi */ \
    RDF(ai, CC, 1, wm); \
    P_BAR; P_LGKM; \
    __builtin_amdgcn_s_setprio(1); \
    CHAIN32(ai, br, acci); \
    ai00 = negbf(ai00); ai01 = negbf(ai01); ai10 = negbf(ai10); ai11 = negbf(ai11); \
    CHAIN32(ai, bi, accr); \
    __builtin_amdgcn_s_setprio(0); \
    if (DOSTG) P_VM0; \
    P_BAR; \
} while (0)

    SL0(0, 0); SL1(0, 0); SL2(0, 0); SL3(0, 0);
    SL4(0, 0); SL5(0, 0); SL6(0, 0); SL7(0, 0);
    P_VM0;
    P_BAR;
    for (int t = 0; t < NN / 32 - 1; ++t) {
        const int cc = t & 1, nb = cc ^ 1;
        KSTEP2(cc, nb, (size_t)(t + 1) * 32, 1);
    }
    KSTEP2(1, 0, 0, 0);

    // C/D 32x32: col = l31, row = (e&3) + 8*(e>>2) + 4*kh
    const int kh = kh2 >> 1;
#pragma unroll
    for (int i = 0; i < 2; i++)
#pragma unroll
        for (int j = 0; j < 2; j++) {
            const int col = bcol + wn + j * 32 + l31;
#pragma unroll
            for (int e = 0; e < 16; e++) {
                const int row = brow + wm + i * 32 + (e & 3) + 8 * (e >> 2) + 4 * kh;
                Out[(size_t)row * (2 * NN) + col]      = accr[i][j][e];
                Out[(size_t)row * (2 * NN) + NN + col] = acci[i][j][e];
            }
        }
}

extern "C" void kernel_launch(void* const* d_in, const int* in_sizes, int n_in,
                              void* d_out, int out_size, void* d_ws, size_t ws_size,
                              hipStream_t stream) {
    const float* x  = (const float*)d_in[0];
    const float* Wr = (const float*)d_in[1];
    const float* Wi = (const float*)d_in[2];
    float* out = (float*)d_out;

    const size_t SZ = (size_t)NN * NN;
    u16* ws  = (u16*)d_ws;
    u16* xb  = ws;            // slot 0: bf16 x        (later reused: WrT)
    u16* Wrb = ws + SZ;       // slot 1: bf16 W_r      (later reused: WiT)
    u16* Wib = ws + 2 * SZ;   // slot 2: bf16 W_i
    u16* Rtr = ws + 3 * SZ;   // slot 3: R_r^T bf16
    u16* Rti = ws + 4 * SZ;   // slot 4: R_i^T bf16

    // 1) convert inputs to bf16
    cvt_bf16<<<8192, 256, 0, stream>>>(x,  xb);
    cvt_bf16<<<8192, 256, 0, stream>>>(Wr, Wrb);
    cvt_bf16<<<8192, 256, 0, stream>>>(Wi, Wib);

    // 2) fused pass 1: Rt_r = NT(W_r, x), Rt_i = NT(W_i, x)
    gemm_pass1<<<1024, 256, 0, stream>>>(Wrb, Wib, xb, Rtr, Rti);

    // 3) transposed bf16 weights (reuse slots 0,1)
    u16* WrT = xb;
    u16* WiT = Wrb;
    tr_cvt<<<dim3(128, 128), dim3(32, 8), 0, stream>>>(Wr, WrT);
    tr_cvt<<<dim3(128, 128), dim3(32, 8), 0, stream>>>(Wi, WiT);

    // 4) fused pass 2 -> d_out [NN][2*NN]
    gemm_pass2<<<1024, 256, 0, stream>>>(WrT, WiT, Rtr, Rti, out);
}

// Round 9
// 767.465 us; speedup vs baseline: 1.1146x; 1.1146x over previous
//
#include <hip/hip_runtime.h>
#include <hip/hip_bf16.h>

#define NN 4096

typedef unsigned short u16;
using bf16x8 = __attribute__((ext_vector_type(8))) short;
using f32x4  = __attribute__((ext_vector_type(4))) float;
using u32x4  = __attribute__((ext_vector_type(4))) unsigned int;

// round-to-nearest-even f32 -> bf16 bits
__device__ inline u16 f2bf(float f) {
    union { float f; unsigned u; } c; c.f = f;
    unsigned r = (c.u + 0x7fffu + ((c.u >> 16) & 1u)) >> 16;
    return (u16)r;
}

__device__ inline void gld16(const void* g, void* l) {
    __builtin_amdgcn_global_load_lds(
        (const __attribute__((address_space(1))) void*)g,
        (__attribute__((address_space(3))) void*)l, 16, 0, 0);
}

__device__ inline bf16x8 negbf(bf16x8 v) {
    u32x4 u; __builtin_memcpy(&u, &v, 16);
    u ^= 0x80008000u;
    bf16x8 r; __builtin_memcpy(&r, &u, 16);
    return r;
}

// ---------------- f32 -> bf16 convert ----------------
__global__ __launch_bounds__(256) void cvt_bf16(const float* __restrict__ s,
                                                u16* __restrict__ d) {
    size_t i = ((size_t)blockIdx.x * 256 + threadIdx.x) * 8;
    float4 v0 = *(const float4*)(s + i);
    float4 v1 = *(const float4*)(s + i + 4);
    bf16x8 o;
    o[0] = (short)f2bf(v0.x); o[1] = (short)f2bf(v0.y);
    o[2] = (short)f2bf(v0.z); o[3] = (short)f2bf(v0.w);
    o[4] = (short)f2bf(v1.x); o[5] = (short)f2bf(v1.y);
    o[6] = (short)f2bf(v1.z); o[7] = (short)f2bf(v1.w);
    *(bf16x8*)(d + i) = o;
}

// ---------------- transpose + convert: d[m][k] = bf16(s[k][m]) ----------------
__global__ __launch_bounds__(256) void tr_cvt(const float* __restrict__ s,
                                              u16* __restrict__ d) {
    __shared__ float t[32][33];
    int x  = blockIdx.x * 32 + threadIdx.x;
    int y0 = blockIdx.y * 32;
#pragma unroll
    for (int j = 0; j < 32; j += 8)
        t[threadIdx.y + j][threadIdx.x] = s[(size_t)(y0 + threadIdx.y + j) * NN + x];
    __syncthreads();
    int x2 = blockIdx.y * 32 + threadIdx.x;
    int y2 = blockIdx.x * 32;
#pragma unroll
    for (int j = 0; j < 32; j += 8)
        d[(size_t)(y2 + threadIdx.y + j) * NN + x2] = f2bf(t[threadIdx.x][threadIdx.y + j]);
}

// ---- phase primitives (rule #18: sched_barrier after inline waitcnt) ----
#define P_BAR  __builtin_amdgcn_s_barrier()
#define P_LGKM do { asm volatile("s_waitcnt lgkmcnt(0)" ::: "memory"); \
                    __builtin_amdgcn_sched_barrier(0); } while (0)
#define P_VM0  do { asm volatile("s_waitcnt vmcnt(0)" ::: "memory"); \
                    __builtin_amdgcn_sched_barrier(0); } while (0)

#define CHAIN(AF, BF, ACC) do { \
    __builtin_amdgcn_s_setprio(1); \
    _Pragma("unroll") \
    for (int i_ = 0; i_ < 4; i_++) \
        _Pragma("unroll") \
        for (int j_ = 0; j_ < 4; j_++) \
            ACC[i_][j_] = __builtin_amdgcn_mfma_f32_16x16x32_bf16(AF[i_], BF[j_], ACC[i_][j_], 0, 0, 0); \
    __builtin_amdgcn_s_setprio(0); \
} while (0)

// read 4 fragments from sm[cc][TILE], rows BASE+{0,16,32,48}+rl
#define RD4(DST, CC, TILE, BASE) do { \
    _Pragma("unroll") \
    for (int i_ = 0; i_ < 4; i_++) \
        DST[i_] = *(const bf16x8*)&sm[CC][TILE][((BASE) + i_ * 16 + rl) * 32 + kg]; \
} while (0)

// LDS swizzle (both GEMMs): physical 16B-block p at row r holds logical block
// p ^ ((r>>1)&3); staged via inverse-permuted GLOBAL source (gld_lds dest
// linear, rule #21); read back with same XOR. Conflict-free (R3: 3.35e7->0).
// NOTE: the natural 32x32-MFMA read pattern conflicts (+4 cyc/b128, R7/R8
// measured, two different remaps) -- stay on 16x16 fragments.

// ---------------- pass 1 (FUSED, 2-phase K-step): Rtr=NT(Wr,x), Rti=NT(Wi,x) --
__global__ __launch_bounds__(256, 2) void gemm_pass1(
    const u16* __restrict__ Ar, const u16* __restrict__ Ai,
    const u16* __restrict__ B,
    u16* __restrict__ Cr, u16* __restrict__ Ci) {
    __shared__ u16 sm[2][3][4096];   // [buf][Wr,Wi,x] = 48 KB

    const int brow = blockIdx.y * 128;
    const int bcol = blockIdx.x * 128;

    const int tid  = threadIdx.x;
    const int lane = tid & 63;
    const int wid  = tid >> 6;
    const int wm   = (wid >> 1) * 64;
    const int wn   = (wid & 1) * 64;

    f32x4 accr[4][4] = {};
    f32x4 acci[4][4] = {};

    const int r0 = tid >> 2;
    const int lb = (tid & 3) ^ ((r0 >> 1) & 3);
    const size_t aoff0 = (size_t)(brow + r0) * NN + lb * 8;
    const size_t aoff1 = aoff0 + (size_t)64 * NN;
    const size_t boff0 = (size_t)(bcol + r0) * NN + lb * 8;
    const size_t boff1 = boff0 + (size_t)64 * NN;
    const int rl = lane & 15;
    const int kg = ((lane >> 4) ^ ((rl >> 1) & 3)) * 8;

#define T0(b, kk) gld16(Ar + aoff0 + (kk), &sm[b][0][tid * 8])
#define T1(b, kk) gld16(Ar + aoff1 + (kk), &sm[b][0][2048 + tid * 8])
#define T2(b, kk) gld16(Ai + aoff0 + (kk), &sm[b][1][tid * 8])
#define T3(b, kk) gld16(Ai + aoff1 + (kk), &sm[b][1][2048 + tid * 8])
#define T4(b, kk) gld16(B  + boff0 + (kk), &sm[b][2][tid * 8])
#define T5(b, kk) gld16(B  + boff1 + (kk), &sm[b][2][2048 + tid * 8])

// one barrier per phase (alignment); the only correctness barrier is the
// post-VM0 one (stage writes nb, reads read cc; own reads drained by LGKM)
#define KSTEP1(CC, NB, KN, DOSTG) do { \
    bf16x8 af[4], ag[4], bb[4]; \
    RD4(af, CC, 0, wm); RD4(bb, CC, 2, wn); \
    if (DOSTG) { T0(NB, KN); T1(NB, KN); T2(NB, KN); T3(NB, KN); } \
    P_BAR; P_LGKM; \
    CHAIN(af, bb, accr); \
    RD4(ag, CC, 1, wm); \
    if (DOSTG) { T4(NB, KN); T5(NB, KN); } \
    P_BAR; P_LGKM; \
    CHAIN(ag, bb, acci); \
    if (DOSTG) P_VM0; \
    P_BAR; \
} while (0)

    T0(0, 0); T1(0, 0); T2(0, 0); T3(0, 0); T4(0, 0); T5(0, 0);
    P_VM0;
    P_BAR;
    for (int t = 0; t < NN / 32 - 1; ++t) {
        const int cc = t & 1, nb = cc ^ 1;
        KSTEP1(cc, nb, (size_t)(t + 1) * 32, 1);
    }
    KSTEP1(1, 0, 0, 0);

    const int rg = (lane >> 4) * 4;
#pragma unroll
    for (int i = 0; i < 4; i++)
#pragma unroll
        for (int j = 0; j < 4; j++) {
            int col = bcol + wn + j * 16 + rl;
#pragma unroll
            for (int r = 0; r < 4; r++) {
                int row = brow + wm + i * 16 + rg + r;
                Cr[(size_t)row * NN + col] = f2bf(accr[i][j][r]);
                Ci[(size_t)row * NN + col] = f2bf(acci[i][j][r]);
            }
        }
}

// ------- pass 2 (FUSED dual complex, 4-phase K-step = 4 product chains) -------
// C_r[m,n] = sum_k Ar[m,k]Br[n,k] - Ai[m,k]Bi[n,k]
// C_i[m,n] = sum_k Ar[m,k]Bi[n,k] + Ai[m,k]Br[n,k]
__global__ __launch_bounds__(256, 2) void gemm_pass2(
    const u16* __restrict__ Ar, const u16* __restrict__ Ai,
    const u16* __restrict__ Br, const u16* __restrict__ Bi,
    float* __restrict__ Out) {
    __shared__ u16 sm[2][4][4096];   // [buf][Ar,Ai,Br,Bi] = 64 KB

    const int brow = blockIdx.y * 128;
    const int bcol = blockIdx.x * 128;

    const int tid  = threadIdx.x;
    const int lane = tid & 63;
    const int wid  = tid >> 6;
    const int wm   = (wid >> 1) * 64;
    const int wn   = (wid & 1) * 64;

    f32x4 accr[4][4] = {};
    f32x4 acci[4][4] = {};

    const int r0 = tid >> 2;
    const int lb = (tid & 3) ^ ((r0 >> 1) & 3);
    const size_t moff0 = (size_t)(brow + r0) * NN + lb * 8;
    const size_t moff1 = moff0 + (size_t)64 * NN;
    const size_t noff0 = (size_t)(bcol + r0) * NN + lb * 8;
    const size_t noff1 = noff0 + (size_t)64 * NN;
    const int rl = lane & 15;
    const int kg = ((lane >> 4) ^ ((rl >> 1) & 3)) * 8;

#define SL0(b, kk) gld16(Ar + moff0 + (kk), &sm[b][0][tid * 8])
#define SL1(b, kk) gld16(Ar + moff1 + (kk), &sm[b][0][2048 + tid * 8])
#define SL2(b, kk) gld16(Ai + moff0 + (kk), &sm[b][1][tid * 8])
#define SL3(b, kk) gld16(Ai + moff1 + (kk), &sm[b][1][2048 + tid * 8])
#define SL4(b, kk) gld16(Br + noff0 + (kk), &sm[b][2][tid * 8])
#define SL5(b, kk) gld16(Br + noff1 + (kk), &sm[b][2][2048 + tid * 8])
#define SL6(b, kk) gld16(Bi + noff0 + (kk), &sm[b][3][tid * 8])
#define SL7(b, kk) gld16(Bi + noff1 + (kk), &sm[b][3][2048 + tid * 8])

#define KSTEP2(CC, NB, KN, DOSTG) do { \
    bf16x8 ar[4], ai[4], br[4], bi[4]; \
    /* P0: acci += ar*bi */ \
    RD4(ar, CC, 0, wm); RD4(bi, CC, 3, wn); \
    if (DOSTG) { SL0(NB, KN); SL1(NB, KN); SL2(NB, KN); } \
    P_BAR; P_LGKM; \
    CHAIN(ar, bi, acci); \
    /* P1: accr += ar*br */ \
    RD4(br, CC, 2, wn); \
    if (DOSTG) { SL3(NB, KN); SL4(NB, KN); SL5(NB, KN); } \
    P_BAR; P_LGKM; \
    CHAIN(ar, br, accr); \
    /* P2: acci += ai*br */ \
    RD4(ai, CC, 1, wm); \
    if (DOSTG) { SL6(NB, KN); SL7(NB, KN); } \
    P_BAR; P_LGKM; \
    CHAIN(ai, br, acci); \
    /* P3: accr += (-ai)*bi */ \
    _Pragma("unroll") for (int i_ = 0; i_ < 4; i_++) ai[i_] = negbf(ai[i_]); \
    CHAIN(ai, bi, accr); \
    if (DOSTG) P_VM0; \
    P_BAR; \
} while (0)

    SL0(0, 0); SL1(0, 0); SL2(0, 0); SL3(0, 0);
    SL4(0, 0); SL5(0, 0); SL6(0, 0); SL7(0, 0);
    P_VM0;
    P_BAR;
    for (int t = 0; t < NN / 32 - 1; ++t) {
        const int cc = t & 1, nb = cc ^ 1;
        KSTEP2(cc, nb, (size_t)(t + 1) * 32, 1);
    }
    KSTEP2(1, 0, 0, 0);

    const int rg = (lane >> 4) * 4;
#pragma unroll
    for (int i = 0; i < 4; i++)
#pragma unroll
        for (int j = 0; j < 4; j++) {
            int col = bcol + wn + j * 16 + rl;
#pragma unroll
            for (int r = 0; r < 4; r++) {
                int row = brow + wm + i * 16 + rg + r;
                Out[(size_t)row * (2 * NN) + col]      = accr[i][j][r];
                Out[(size_t)row * (2 * NN) + NN + col] = acci[i][j][r];
            }
        }
}

extern "C" void kernel_launch(void* const* d_in, const int* in_sizes, int n_in,
                              void* d_out, int out_size, void* d_ws, size_t ws_size,
                              hipStream_t stream) {
    const float* x  = (const float*)d_in[0];
    const float* Wr = (const float*)d_in[1];
    const float* Wi = (const float*)d_in[2];
    float* out = (float*)d_out;

    const size_t SZ = (size_t)NN * NN;
    u16* ws  = (u16*)d_ws;
    u16* xb  = ws;            // slot 0: bf16 x        (later reused: WrT)
    u16* Wrb = ws + SZ;       // slot 1: bf16 W_r      (later reused: WiT)
    u16* Wib = ws + 2 * SZ;   // slot 2: bf16 W_i
    u16* Rtr = ws + 3 * SZ;   // slot 3: R_r^T bf16
    u16* Rti = ws + 4 * SZ;   // slot 4: R_i^T bf16

    // 1) convert inputs to bf16
    cvt_bf16<<<8192, 256, 0, stream>>>(x,  xb);
    cvt_bf16<<<8192, 256, 0, stream>>>(Wr, Wrb);
    cvt_bf16<<<8192, 256, 0, stream>>>(Wi, Wib);

    // 2) fused pass 1: Rt_r = NT(W_r, x), Rt_i = NT(W_i, x)
    gemm_pass1<<<dim3(32, 32), 256, 0, stream>>>(Wrb, Wib, xb, Rtr, Rti);

    // 3) transposed bf16 weights (reuse slots 0,1)
    u16* WrT = xb;
    u16* WiT = Wrb;
    tr_cvt<<<dim3(128, 128), dim3(32, 8), 0, stream>>>(Wr, WrT);
    tr_cvt<<<dim3(128, 128), dim3(32, 8), 0, stream>>>(Wi, WiT);

    // 4) fused pass 2 -> d_out [NN][2*NN]
    gemm_pass2<<<dim3(32, 32), 256, 0, stream>>>(WrT, WiT, Rtr, Rti, out);
}

// Round 10
// 763.110 us; speedup vs baseline: 1.1209x; 1.0057x over previous
//
#include <hip/hip_runtime.h>
#include <hip/hip_bf16.h>

#define NN 4096

typedef unsigned short u16;
using bf16x8 = __attribute__((ext_vector_type(8))) short;
using f32x4  = __attribute__((ext_vector_type(4))) float;
using u32x4  = __attribute__((ext_vector_type(4))) unsigned int;

// round-to-nearest-even f32 -> bf16 bits
__device__ inline u16 f2bf(float f) {
    union { float f; unsigned u; } c; c.f = f;
    unsigned r = (c.u + 0x7fffu + ((c.u >> 16) & 1u)) >> 16;
    return (u16)r;
}

__device__ inline void gld16(const void* g, void* l) {
    __builtin_amdgcn_global_load_lds(
        (const __attribute__((address_space(1))) void*)g,
        (__attribute__((address_space(3))) void*)l, 16, 0, 0);
}

__device__ inline bf16x8 negbf(bf16x8 v) {
    u32x4 u; __builtin_memcpy(&u, &v, 16);
    u ^= 0x80008000u;
    bf16x8 r; __builtin_memcpy(&r, &u, 16);
    return r;
}

// ---------------- f32 -> bf16 convert ----------------
__global__ __launch_bounds__(256) void cvt_bf16(const float* __restrict__ s,
                                                u16* __restrict__ d) {
    size_t i = ((size_t)blockIdx.x * 256 + threadIdx.x) * 8;
    float4 v0 = *(const float4*)(s + i);
    float4 v1 = *(const float4*)(s + i + 4);
    bf16x8 o;
    o[0] = (short)f2bf(v0.x); o[1] = (short)f2bf(v0.y);
    o[2] = (short)f2bf(v0.z); o[3] = (short)f2bf(v0.w);
    o[4] = (short)f2bf(v1.x); o[5] = (short)f2bf(v1.y);
    o[6] = (short)f2bf(v1.z); o[7] = (short)f2bf(v1.w);
    *(bf16x8*)(d + i) = o;
}

// ---------------- transpose + convert: d[m][k] = bf16(s[k][m]) ----------------
__global__ __launch_bounds__(256) void tr_cvt(const float* __restrict__ s,
                                              u16* __restrict__ d) {
    __shared__ float t[32][33];
    int x  = blockIdx.x * 32 + threadIdx.x;
    int y0 = blockIdx.y * 32;
#pragma unroll
    for (int j = 0; j < 32; j += 8)
        t[threadIdx.y + j][threadIdx.x] = s[(size_t)(y0 + threadIdx.y + j) * NN + x];
    __syncthreads();
    int x2 = blockIdx.y * 32 + threadIdx.x;
    int y2 = blockIdx.x * 32;
#pragma unroll
    for (int j = 0; j < 32; j += 8)
        d[(size_t)(y2 + threadIdx.y + j) * NN + x2] = f2bf(t[threadIdx.x][threadIdx.y + j]);
}

// ---- sync primitives (rule #18: sched_barrier after inline waitcnt) ----
#define P_BAR  __builtin_amdgcn_s_barrier()
#define P_LGKM do { asm volatile("s_waitcnt lgkmcnt(0)" ::: "memory"); \
                    __builtin_amdgcn_sched_barrier(0); } while (0)
#define VMW(N) do { asm volatile("s_waitcnt vmcnt(" #N ")" ::: "memory"); \
                    __builtin_amdgcn_sched_barrier(0); } while (0)

#define CHAIN(AF, BF, ACC) do { \
    __builtin_amdgcn_s_setprio(1); \
    _Pragma("unroll") \
    for (int i_ = 0; i_ < 4; i_++) \
        _Pragma("unroll") \
        for (int j_ = 0; j_ < 4; j_++) \
            ACC[i_][j_] = __builtin_amdgcn_mfma_f32_16x16x32_bf16(AF[i_], BF[j_], ACC[i_][j_], 0, 0, 0); \
    __builtin_amdgcn_s_setprio(0); \
} while (0)

// read 4 fragments from sm[cc][TILE], rows BASE+{0,16,32,48}+rl
#define RD4(DST, CC, TILE, BASE) do { \
    _Pragma("unroll") \
    for (int i_ = 0; i_ < 4; i_++) \
        DST[i_] = *(const bf16x8*)&sm[CC][TILE][((BASE) + i_ * 16 + rl) * 32 + kg]; \
} while (0)

// LDS swizzle: physical 16B-block p at row r holds logical p ^ ((r>>1)&3);
// staged via inverse-permuted GLOBAL source (gld_lds dest linear, rule #21);
// read back with same XOR. Conflict-free (R3: 3.35e7 -> 0).
//
// T4 counted-vmcnt scheme (this round): each K-step's tiles split into two
// half-sets staged at different phases; per-phase waits are counted (6/4/4),
// never 0 in the main loop. Every ds_read's data is guaranteed by a
// vmcnt+barrier >=1 phase before its issue; each wave's lgkmcnt(0) precedes
// the next barrier that precedes any overwrite-issue of the same tiles.

// ---------------- pass 1 (FUSED, 2-phase): Rtr=NT(Wr,x), Rti=NT(Wi,x) --------
__global__ __launch_bounds__(256, 2) void gemm_pass1(
    const u16* __restrict__ Ar, const u16* __restrict__ Ai,
    const u16* __restrict__ B,
    u16* __restrict__ Cr, u16* __restrict__ Ci) {
    __shared__ u16 sm[2][3][4096];   // [buf][Wr,Wi,x] = 48 KB

    const int brow = blockIdx.y * 128;
    const int bcol = blockIdx.x * 128;

    const int tid  = threadIdx.x;
    const int lane = tid & 63;
    const int wid  = tid >> 6;
    const int wm   = (wid >> 1) * 64;
    const int wn   = (wid & 1) * 64;

    f32x4 accr[4][4] = {};
    f32x4 acci[4][4] = {};

    const int r0 = tid >> 2;
    const int lb = (tid & 3) ^ ((r0 >> 1) & 3);
    const size_t aoff0 = (size_t)(brow + r0) * NN + lb * 8;
    const size_t aoff1 = aoff0 + (size_t)64 * NN;
    const size_t boff0 = (size_t)(bcol + r0) * NN + lb * 8;
    const size_t boff1 = boff0 + (size_t)64 * NN;
    const int rl = lane & 15;
    const int kg = ((lane >> 4) ^ ((rl >> 1) & 3)) * 8;

#define T0(b, kk) gld16(Ar + aoff0 + (kk), &sm[b][0][tid * 8])
#define T1(b, kk) gld16(Ar + aoff1 + (kk), &sm[b][0][2048 + tid * 8])
#define T2(b, kk) gld16(Ai + aoff0 + (kk), &sm[b][1][tid * 8])
#define T3(b, kk) gld16(Ai + aoff1 + (kk), &sm[b][1][2048 + tid * 8])
#define T4(b, kk) gld16(B  + boff0 + (kk), &sm[b][2][tid * 8])
#define T5(b, kk) gld16(B  + boff1 + (kk), &sm[b][2][2048 + tid * 8])

// half-A = {Wr, x} (4 lines, issued P0, consumed next P0)
// half-B = {Wi}    (2 lines, issued P1, consumed next P1)
// V0 guarantees this step's Wi for P1's read; V1 guarantees next step's half-A.
#define KSTEP1(CC, NB, KN, DOSTG, V0, V1) do { \
    bf16x8 af[4], ag[4], bb[4]; \
    RD4(af, CC, 0, wm); RD4(bb, CC, 2, wn); \
    if (DOSTG) { T0(NB, KN); T1(NB, KN); T4(NB, KN); T5(NB, KN); } \
    VMW(V0); P_BAR; P_LGKM; \
    CHAIN(af, bb, accr); \
    RD4(ag, CC, 1, wm); \
    P_LGKM; \
    if (DOSTG) { T2(NB, KN); T3(NB, KN); } \
    VMW(V1); P_BAR; \
    CHAIN(ag, bb, acci); \
} while (0)

    // prologue: stage buf0 (half-A then half-B order), guarantee half-A(0)
    T0(0, 0); T1(0, 0); T4(0, 0); T5(0, 0); T2(0, 0); T3(0, 0);
    VMW(2); P_BAR;
    for (int t = 0; t < NN / 32 - 1; ++t) {
        const int cc = t & 1, nb = cc ^ 1;
        KSTEP1(cc, nb, (size_t)(t + 1) * 32, 1, 4, 2);
    }
    KSTEP1(1, 0, 0, 0, 0, 0);

    const int rg = (lane >> 4) * 4;
#pragma unroll
    for (int i = 0; i < 4; i++)
#pragma unroll
        for (int j = 0; j < 4; j++) {
            int col = bcol + wn + j * 16 + rl;
#pragma unroll
            for (int r = 0; r < 4; r++) {
                int row = brow + wm + i * 16 + rg + r;
                Cr[(size_t)row * NN + col] = f2bf(accr[i][j][r]);
                Ci[(size_t)row * NN + col] = f2bf(acci[i][j][r]);
            }
        }
}

// ------- pass 2 (FUSED dual complex, 4 chains, counted vmcnt) ----------------
// C_r[m,n] = sum_k Ar[m,k]Br[n,k] - Ai[m,k]Bi[n,k]
// C_i[m,n] = sum_k Ar[m,k]Bi[n,k] + Ai[m,k]Br[n,k]
__global__ __launch_bounds__(256, 2) void gemm_pass2(
    const u16* __restrict__ Ar, const u16* __restrict__ Ai,
    const u16* __restrict__ Br, const u16* __restrict__ Bi,
    float* __restrict__ Out) {
    __shared__ u16 sm[2][4][4096];   // [buf][Ar,Ai,Br,Bi] = 64 KB

    const int brow = blockIdx.y * 128;
    const int bcol = blockIdx.x * 128;

    const int tid  = threadIdx.x;
    const int lane = tid & 63;
    const int wid  = tid >> 6;
    const int wm   = (wid >> 1) * 64;
    const int wn   = (wid & 1) * 64;

    f32x4 accr[4][4] = {};
    f32x4 acci[4][4] = {};

    const int r0 = tid >> 2;
    const int lb = (tid & 3) ^ ((r0 >> 1) & 3);
    const size_t moff0 = (size_t)(brow + r0) * NN + lb * 8;
    const size_t moff1 = moff0 + (size_t)64 * NN;
    const size_t noff0 = (size_t)(bcol + r0) * NN + lb * 8;
    const size_t noff1 = noff0 + (size_t)64 * NN;
    const int rl = lane & 15;
    const int kg = ((lane >> 4) ^ ((rl >> 1) & 3)) * 8;

#define SL0(b, kk) gld16(Ar + moff0 + (kk), &sm[b][0][tid * 8])
#define SL1(b, kk) gld16(Ar + moff1 + (kk), &sm[b][0][2048 + tid * 8])
#define SL2(b, kk) gld16(Ai + moff0 + (kk), &sm[b][1][tid * 8])
#define SL3(b, kk) gld16(Ai + moff1 + (kk), &sm[b][1][2048 + tid * 8])
#define SL4(b, kk) gld16(Br + noff0 + (kk), &sm[b][2][tid * 8])
#define SL5(b, kk) gld16(Br + noff1 + (kk), &sm[b][2][2048 + tid * 8])
#define SL6(b, kk) gld16(Bi + noff0 + (kk), &sm[b][3][tid * 8])
#define SL7(b, kk) gld16(Bi + noff1 + (kk), &sm[b][3][2048 + tid * 8])

// half-A = {Ar, Bi} (4 lines, issued P0, consumed next P0)
// half-B = {Br, Ai} (4 lines, Br first, issued P2, consumed next P1/P2)
// V0 guarantees this step's Br; V1 this step's Ai; V2 next step's half-A.
#define KSTEP2(CC, NB, KN, DOSTG, V0, V1, V2) do { \
    bf16x8 ar[4], ai[4], br[4], bi[4]; \
    /* P0: acci += ar*bi */ \
    RD4(ar, CC, 0, wm); RD4(bi, CC, 3, wn); \
    if (DOSTG) { SL0(NB, KN); SL1(NB, KN); SL6(NB, KN); SL7(NB, KN); } \
    VMW(V0); P_BAR; P_LGKM; \
    CHAIN(ar, bi, acci); \
    /* P1: accr += ar*br */ \
    RD4(br, CC, 2, wn); \
    P_LGKM; \
    VMW(V1); P_BAR; \
    CHAIN(ar, br, accr); \
    /* P2: acci += ai*br */ \
    RD4(ai, CC, 1, wm); \
    P_LGKM; \
    if (DOSTG) { SL4(NB, KN); SL5(NB, KN); SL2(NB, KN); SL3(NB, KN); } \
    VMW(V2); P_BAR; \
    CHAIN(ai, br, acci); \
    /* P3: accr += (-ai)*bi  (regs only, no sync) */ \
    _Pragma("unroll") for (int i_ = 0; i_ < 4; i_++) ai[i_] = negbf(ai[i_]); \
    CHAIN(ai, bi, accr); \
} while (0)

    // prologue: stage buf0 (half-A then half-B), guarantee half-A(0)
    SL0(0, 0); SL1(0, 0); SL6(0, 0); SL7(0, 0);
    SL4(0, 0); SL5(0, 0); SL2(0, 0); SL3(0, 0);
    VMW(4); P_BAR;
    for (int t = 0; t < NN / 32 - 1; ++t) {
        const int cc = t & 1, nb = cc ^ 1;
        KSTEP2(cc, nb, (size_t)(t + 1) * 32, 1, 6, 4, 4);
    }
    KSTEP2(1, 0, 0, 0, 2, 0, 0);

    const int rg = (lane >> 4) * 4;
#pragma unroll
    for (int i = 0; i < 4; i++)
#pragma unroll
        for (int j = 0; j < 4; j++) {
            int col = bcol + wn + j * 16 + rl;
#pragma unroll
            for (int r = 0; r < 4; r++) {
                int row = brow + wm + i * 16 + rg + r;
                Out[(size_t)row * (2 * NN) + col]      = accr[i][j][r];
                Out[(size_t)row * (2 * NN) + NN + col] = acci[i][j][r];
            }
        }
}

extern "C" void kernel_launch(void* const* d_in, const int* in_sizes, int n_in,
                              void* d_out, int out_size, void* d_ws, size_t ws_size,
                              hipStream_t stream) {
    const float* x  = (const float*)d_in[0];
    const float* Wr = (const float*)d_in[1];
    const float* Wi = (const float*)d_in[2];
    float* out = (float*)d_out;

    const size_t SZ = (size_t)NN * NN;
    u16* ws  = (u16*)d_ws;
    u16* xb  = ws;            // slot 0: bf16 x        (later reused: WrT)
    u16* Wrb = ws + SZ;       // slot 1: bf16 W_r      (later reused: WiT)
    u16* Wib = ws + 2 * SZ;   // slot 2: bf16 W_i
    u16* Rtr = ws + 3 * SZ;   // slot 3: R_r^T bf16
    u16* Rti = ws + 4 * SZ;   // slot 4: R_i^T bf16

    // 1) convert inputs to bf16
    cvt_bf16<<<8192, 256, 0, stream>>>(x,  xb);
    cvt_bf16<<<8192, 256, 0, stream>>>(Wr, Wrb);
    cvt_bf16<<<8192, 256, 0, stream>>>(Wi, Wib);

    // 2) fused pass 1: Rt_r = NT(W_r, x), Rt_i = NT(W_i, x)
    gemm_pass1<<<dim3(32, 32), 256, 0, stream>>>(Wrb, Wib, xb, Rtr, Rti);

    // 3) transposed bf16 weights (reuse slots 0,1)
    u16* WrT = xb;
    u16* WiT = Wrb;
    tr_cvt<<<dim3(128, 128), dim3(32, 8), 0, stream>>>(Wr, WrT);
    tr_cvt<<<dim3(128, 128), dim3(32, 8), 0, stream>>>(Wi, WiT);

    // 4) fused pass 2 -> d_out [NN][2*NN]
    gemm_pass2<<<dim3(32, 32), 256, 0, stream>>>(WrT, WiT, Rtr, Rti, out);
}